// Round 6
// baseline (369.353 us; speedup 1.0000x reference)
//
#include <hip/hip_runtime.h>

#define SEQ   1024
#define BATCH 512
#define NC    48
#define CH    8

__device__ __forceinline__ float rfl(float x) {
    return __int_as_float(__builtin_amdgcn_readfirstlane(__float_as_int(x)));
}
__device__ __forceinline__ float rlane(float x, int l) {
    return __int_as_float(__builtin_amdgcn_readlane(__float_as_int(x), l));
}

// Bidirectional meet-in-the-middle CRF forward. One wave per batch element.
// Z = alpha_m^T beta_m: the forward chain (t=0..m) and backward chain
// (t=L-1..m) are INDEPENDENT, so one wave runs both concurrently — each wall
// iteration advances both chains one step, halving wall iterations (1023->512)
// and overlapping the ~300 cyc/step dependency/cadence stall measured in R5
// (558 cyc/step vs ~220 cyc of VALU issue).
//   fwd:  z[j]    <- (sum_i z[i] *E[i][j]) * w_t[j]   * 2^-exf   (E col pinned)
//   bwd:  beta[i] <- (sum_j E[i][j]*(beta[j]*w_{t+1}[j]))* 2^-exb (E row pinned)
// w = exp2(score*log2e) precomputed per staged chunk (off the dependent path);
// rescale factors 2^-ex constructed by scalar bit ops from readfirstlane
// exponent; Sf/Sb accumulate exponents exactly. Broadcast via v_readlane ->
// SGPR operand FMAs (R5: beats LDS roundtrip). Scores staged in CH=8
// register chunks per stream, double-buffered, expified one chunk behind the
// loads so vmcnt waits land on ~5000-cycle-old loads.
__global__ __launch_bounds__(64, 1) void crf_fwd(
    const float* __restrict__ scores,   // [SEQ][BATCH][NC]
    const int*   __restrict__ target,   // [SEQ][BATCH]
    const int*   __restrict__ lengths,  // [BATCH]
    const float* __restrict__ trans,    // [NC][NC]
    float* __restrict__ out)            // [2*BATCH]: X, then X - logZ
{
    const int b    = blockIdx.x;
    const int lane = threadIdx.x;
    const int jc   = (lane < NC) ? lane : (NC - 1);   // lanes 48-63 mirror 47 (never read)
    const int L    = lengths[b];                       // uniform within block
    const int m    = (L - 1) >> 1;                     // fwd steps: t = 1..m
    const int nb   = (L - 1) - m;                      // bwd steps: t = L-2 .. m  (nb >= m)
    const float LOG2E = 1.4426950408889634f;
    const float LN2   = 0.6931471805599453f;
    const size_t TS = (size_t)BATCH * NC;
    const float* sp = scores + (size_t)b * NC + jc;

    // ---- staged score chunks: fwd ascending (t=1+k), bwd descending (t=L-1-k) ----
    float FA[CH], FB[CH], BA[CH], BB[CH];
    #define LOADF(buf, kbase) do { \
        _Pragma("unroll") \
        for (int kk_ = 0; kk_ < CH; ++kk_) { \
            int tt_ = 1 + (kbase) + kk_; if (tt_ > SEQ - 1) tt_ = SEQ - 1; \
            (buf)[kk_] = sp[(size_t)tt_ * TS]; \
        } } while (0)
    #define LOADB(buf, kbase) do { \
        _Pragma("unroll") \
        for (int kk_ = 0; kk_ < CH; ++kk_) { \
            int tt_ = L - 1 - ((kbase) + kk_); if (tt_ < 0) tt_ = 0; \
            (buf)[kk_] = sp[(size_t)tt_ * TS]; \
        } } while (0)
    #define EXPIFY(buf) do { \
        _Pragma("unroll") \
        for (int kk_ = 0; kk_ < CH; ++kk_) \
            (buf)[kk_] = __builtin_amdgcn_exp2f((buf)[kk_] * LOG2E); \
        } while (0)

    float s0v = sp[0];
    LOADF(FA, 0);  LOADB(BA, 0);
    LOADF(FB, CH); LOADB(BB, CH);

    // ---- target path score X (parallel over t, then reduce) ----
    float x = 0.f;
    #pragma unroll 4
    for (int t = lane; t < L; t += 64) {
        int cur = target[t * BATCH + b];
        float e = scores[(size_t)t * TS + (size_t)b * NC + cur];
        float tr = 0.f;
        if (t > 0) {
            int prev = target[(t - 1) * BATCH + b];
            tr = trans[prev * NC + cur];
        }
        x += e + tr;
    }
    #pragma unroll
    for (int k = 32; k >= 1; k >>= 1) x += __shfl_xor(x, k, 64);

    // ---- pinned E column (fwd) and E row (bwd) for this lane ----
    #define DECLEF(i) float ef##i = __builtin_amdgcn_exp2f(trans[(i)*NC + jc] * LOG2E); \
                      asm("" : "+v"(ef##i));
    #define DECLEB(i) float eb##i = __builtin_amdgcn_exp2f(trans[jc*NC + (i)] * LOG2E); \
                      asm("" : "+v"(eb##i));
    DECLEF(0)  DECLEF(1)  DECLEF(2)  DECLEF(3)  DECLEF(4)  DECLEF(5)  DECLEF(6)  DECLEF(7)
    DECLEF(8)  DECLEF(9)  DECLEF(10) DECLEF(11) DECLEF(12) DECLEF(13) DECLEF(14) DECLEF(15)
    DECLEF(16) DECLEF(17) DECLEF(18) DECLEF(19) DECLEF(20) DECLEF(21) DECLEF(22) DECLEF(23)
    DECLEF(24) DECLEF(25) DECLEF(26) DECLEF(27) DECLEF(28) DECLEF(29) DECLEF(30) DECLEF(31)
    DECLEF(32) DECLEF(33) DECLEF(34) DECLEF(35) DECLEF(36) DECLEF(37) DECLEF(38) DECLEF(39)
    DECLEF(40) DECLEF(41) DECLEF(42) DECLEF(43) DECLEF(44) DECLEF(45) DECLEF(46) DECLEF(47)
    DECLEB(0)  DECLEB(1)  DECLEB(2)  DECLEB(3)  DECLEB(4)  DECLEB(5)  DECLEB(6)  DECLEB(7)
    DECLEB(8)  DECLEB(9)  DECLEB(10) DECLEB(11) DECLEB(12) DECLEB(13) DECLEB(14) DECLEB(15)
    DECLEB(16) DECLEB(17) DECLEB(18) DECLEB(19) DECLEB(20) DECLEB(21) DECLEB(22) DECLEB(23)
    DECLEB(24) DECLEB(25) DECLEB(26) DECLEB(27) DECLEB(28) DECLEB(29) DECLEB(30) DECLEB(31)
    DECLEB(32) DECLEB(33) DECLEB(34) DECLEB(35) DECLEB(36) DECLEB(37) DECLEB(38) DECLEB(39)
    DECLEB(40) DECLEB(41) DECLEB(42) DECLEB(43) DECLEB(44) DECLEB(45) DECLEB(46) DECLEB(47)
    #undef DECLEF
    #undef DECLEB

    // ---- init: alpha_0 (scaled) and beta_{L-1} = 1 ----
    float s00 = rfl(s0v);
    float z    = __builtin_amdgcn_exp2f((s0v - s00) * LOG2E);
    float Sf   = s00 * LOG2E;
    float beta = 1.0f;
    float Sb   = 0.0f;

    EXPIFY(FA); EXPIFY(BA);   // chunk-0 weights (one-time stall, prologue)

    #define G8F(l0,l1,l2,l3,l4,l5,l6,l7, w0,w1,w2,w3,w4,w5,w6,w7) { \
        float t0_=rlane(z,l0), t1_=rlane(z,l1), t2_=rlane(z,l2), t3_=rlane(z,l3); \
        float t4_=rlane(z,l4), t5_=rlane(z,l5), t6_=rlane(z,l6), t7_=rlane(z,l7); \
        fa0=fmaf(t0_,w0,fa0); fa1=fmaf(t1_,w1,fa1); fa2=fmaf(t2_,w2,fa2); fa3=fmaf(t3_,w3,fa3); \
        fa4=fmaf(t4_,w4,fa4); fa5=fmaf(t5_,w5,fa5); fa6=fmaf(t6_,w6,fa6); fa7=fmaf(t7_,w7,fa7); }
    #define G8B(l0,l1,l2,l3,l4,l5,l6,l7, w0,w1,w2,w3,w4,w5,w6,w7) { \
        float u0_=rlane(cb_,l0), u1_=rlane(cb_,l1), u2_=rlane(cb_,l2), u3_=rlane(cb_,l3); \
        float u4_=rlane(cb_,l4), u5_=rlane(cb_,l5), u6_=rlane(cb_,l6), u7_=rlane(cb_,l7); \
        ba0=fmaf(u0_,w0,ba0); ba1=fmaf(u1_,w1,ba1); ba2=fmaf(u2_,w2,ba2); ba3=fmaf(u3_,w3,ba3); \
        ba4=fmaf(u4_,w4,ba4); ba5=fmaf(u5_,w5,ba5); ba6=fmaf(u6_,w6,ba6); ba7=fmaf(u7_,w7,ba7); }

    // ---- one dual step: advances fwd chain (step k+1) and bwd chain together ----
    #define STEP_DUAL(FW, BW, sidx, kbase) do { \
        const int k_ = (kbase) + (sidx); \
        float rf_  = rfl(z); \
        int   exf_ = ((__float_as_int(rf_) >> 23) & 255) - 126; \
        float pf_  = __int_as_float((127 - exf_) << 23);         /* 2^-exf */ \
        float rb_  = rfl(beta); \
        int   exb_ = ((__float_as_int(rb_) >> 23) & 255) - 126; \
        float pb_  = __int_as_float((127 - exb_) << 23);         /* 2^-exb */ \
        float cb_  = beta * (BW)[sidx]; \
        float fa0=0.f,fa1=0.f,fa2=0.f,fa3=0.f,fa4=0.f,fa5=0.f,fa6=0.f,fa7=0.f; \
        float ba0=0.f,ba1=0.f,ba2=0.f,ba3=0.f,ba4=0.f,ba5=0.f,ba6=0.f,ba7=0.f; \
        G8F( 0, 1, 2, 3, 4, 5, 6, 7,  ef0 ,ef1 ,ef2 ,ef3 ,ef4 ,ef5 ,ef6 ,ef7 ) \
        G8B( 0, 1, 2, 3, 4, 5, 6, 7,  eb0 ,eb1 ,eb2 ,eb3 ,eb4 ,eb5 ,eb6 ,eb7 ) \
        G8F( 8, 9,10,11,12,13,14,15,  ef8 ,ef9 ,ef10,ef11,ef12,ef13,ef14,ef15) \
        G8B( 8, 9,10,11,12,13,14,15,  eb8 ,eb9 ,eb10,eb11,eb12,eb13,eb14,eb15) \
        G8F(16,17,18,19,20,21,22,23,  ef16,ef17,ef18,ef19,ef20,ef21,ef22,ef23) \
        G8B(16,17,18,19,20,21,22,23,  eb16,eb17,eb18,eb19,eb20,eb21,eb22,eb23) \
        G8F(24,25,26,27,28,29,30,31,  ef24,ef25,ef26,ef27,ef28,ef29,ef30,ef31) \
        G8B(24,25,26,27,28,29,30,31,  eb24,eb25,eb26,eb27,eb28,eb29,eb30,eb31) \
        G8F(32,33,34,35,36,37,38,39,  ef32,ef33,ef34,ef35,ef36,ef37,ef38,ef39) \
        G8B(32,33,34,35,36,37,38,39,  eb32,eb33,eb34,eb35,eb36,eb37,eb38,eb39) \
        G8F(40,41,42,43,44,45,46,47,  ef40,ef41,ef42,ef43,ef44,ef45,ef46,ef47) \
        G8B(40,41,42,43,44,45,46,47,  eb40,eb41,eb42,eb43,eb44,eb45,eb46,eb47) \
        float sumf_ = (((fa0+fa4)+(fa1+fa5)) + ((fa2+fa6)+(fa3+fa7))); \
        float sumb_ = (((ba0+ba4)+(ba1+ba5)) + ((ba2+ba6)+(ba3+ba7))); \
        float znew_ = sumf_ * (FW)[sidx] * pf_; \
        float bnew_ = sumb_ * pb_; \
        if (k_ < m)  { z    = znew_; Sf += (float)exf_; }  /* uniform freeze */ \
        if (k_ < nb) { beta = bnew_; Sb += (float)exb_; } \
    } while (0)

    #define CHUNK8(FW, BW, kbase) do { \
        STEP_DUAL(FW,BW,0,kbase); STEP_DUAL(FW,BW,1,kbase); \
        STEP_DUAL(FW,BW,2,kbase); STEP_DUAL(FW,BW,3,kbase); \
        STEP_DUAL(FW,BW,4,kbase); STEP_DUAL(FW,BW,5,kbase); \
        STEP_DUAL(FW,BW,6,kbase); STEP_DUAL(FW,BW,7,kbase); \
    } while (0)

    int k0 = 0;
    while (k0 < nb) {
        CHUNK8(FA, BA, k0);
        EXPIFY(FB); EXPIFY(BB);          // loads issued one chunk ago — aged
        k0 += CH;
        if (k0 >= nb) break;
        LOADF(FA, k0 + CH); LOADB(BA, k0 + CH);
        CHUNK8(FB, BB, k0);
        EXPIFY(FA); EXPIFY(BA);
        k0 += CH;
        LOADF(FB, k0 + CH); LOADB(BB, k0 + CH);
    }
    #undef STEP_DUAL
    #undef CHUNK8
    #undef G8F
    #undef G8B
    #undef LOADF
    #undef LOADB
    #undef EXPIFY

    // ---- finalize: Z = sum_j alpha_m[j]*beta_m[j], logZ = ln2*(log2(sum)+Sf+Sb) ----
    float prod = (lane < NC) ? z * beta : 0.f;
    #pragma unroll
    for (int k = 32; k >= 1; k >>= 1) prod += __shfl_xor(prod, k, 64);
    float logZ = (__builtin_amdgcn_logf(prod) + Sf + Sb) * LN2;

    if (lane == 0) {
        out[b]         = x;          // output 0: X
        out[BATCH + b] = x - logZ;   // output 1: X - logZ
    }
}

extern "C" void kernel_launch(void* const* d_in, const int* in_sizes, int n_in,
                              void* d_out, int out_size, void* d_ws, size_t ws_size,
                              hipStream_t stream) {
    const float* scores  = (const float*)d_in[0];
    const int*   target  = (const int*)d_in[1];
    const int*   lengths = (const int*)d_in[2];
    const float* trans   = (const float*)d_in[3];
    float* out = (float*)d_out;
    crf_fwd<<<BATCH, 64, 0, stream>>>(scores, target, lengths, trans, out);
}